// Round 1
// baseline (6000.894 us; speedup 1.0000x reference)
//
#include <hip/hip_runtime.h>
#include <hip/hip_bf16.h>
#include <cstdint>

#define DEV static __device__ __forceinline__

typedef __attribute__((ext_vector_type(8))) short bf16x8;
typedef __attribute__((ext_vector_type(4))) float f32x4;

// ---------- bf16 helpers (bit-level, no header dependence) ----------
DEV unsigned short f2bf(float f) {
  union { float f; unsigned u; } c; c.f = f;
  unsigned u = c.u;
  return (unsigned short)((u + 0x7fffu + ((u >> 16) & 1u)) >> 16);  // RNE
}
DEV float bf2f(unsigned short h) {
  union { unsigned u; float f; } c; c.u = ((unsigned)h) << 16; return c.f;
}
DEV float bflo(unsigned u) { union { unsigned u; float f; } c; c.u = u << 16; return c.f; }
DEV float bfhi(unsigned u) { union { unsigned u; float f; } c; c.u = u & 0xffff0000u; return c.f; }

// async global->LDS, 16B per lane; LDS dest is wave-uniform base + lane*16
#define ASYNC_COPY16(gsrc, ldst)                                                      \
  __builtin_amdgcn_global_load_lds(                                                   \
      (const __attribute__((address_space(1))) void*)(unsigned long long)(gsrc),      \
      (__attribute__((address_space(3))) void*)(unsigned int)(unsigned long long)(ldst), \
      16, 0, 0)

// =====================================================================
// fp32 -> bf16 weight conversion, 4 elems/thread
// =====================================================================
__global__ void cvt4_kernel(const float* __restrict__ s, unsigned short* __restrict__ d) {
  size_t i = ((size_t)blockIdx.x * 256 + threadIdx.x) * 4;
  float4 v = *(const float4*)(s + i);
  d[i + 0] = f2bf(v.x);
  d[i + 1] = f2bf(v.y);
  d[i + 2] = f2bf(v.z);
  d[i + 3] = f2bf(v.w);
}

// =====================================================================
// embedding + positional encoding: x[bs,d] (fp32 master + bf16 copy)
// =====================================================================
__global__ void embed_kernel(const float* __restrict__ src,    // [B*S,16]
                             const float* __restrict__ emb_w,  // [512,16]
                             const float* __restrict__ emb_b,  // [512]
                             float* __restrict__ x,
                             unsigned short* __restrict__ xb) {
  const int bs = blockIdx.x;        // 0..16383
  const int d = threadIdx.x;        // 0..511
  const int s = bs & 255;
  __shared__ float sv[16];
  if (d < 16) sv[d] = src[(size_t)bs * 16 + d];
  __syncthreads();
  const float* wr = emb_w + (size_t)d * 16;
  float acc = emb_b[d];
#pragma unroll
  for (int v = 0; v < 16; v++) acc += sv[v] * wr[v];
  // posenc: den_i = exp(-(2i) * ln(10000)/512), i = d>>1
  const float den = __expf(-(float)(d & ~1) * (9.2103403719761836f / 512.f));
  const float arg = (float)s * den;
  acc += (d & 1) ? cosf(arg) : sinf(arg);
  x[(size_t)bs * 512 + d] = acc;
  xb[(size_t)bs * 512 + d] = f2bf(acc);
}

// =====================================================================
// bf16 MFMA GEMM, NT: C[m,n] = sum_k A[m,k]*B[n,k] + bias[n]
// 128x128 tile, BK=32, 256 threads (4 waves in 2x2), 4x4 MFMAs/wave
// =====================================================================
template <int RELU, int OUT_BF16>
__global__ __launch_bounds__(256, 2) void gemm_nt(
    const unsigned short* __restrict__ A,   // [M,K] bf16
    const unsigned short* __restrict__ B,   // [N,K] bf16
    const float* __restrict__ bias,         // [N]
    float* __restrict__ Cf,                 // [M,N] if !OUT_BF16
    unsigned short* __restrict__ Cb,        // [M,N] if OUT_BF16
    int M, int N, int K) {
  __shared__ unsigned short As[128 * 32];
  __shared__ unsigned short Bs[128 * 32];
  const int tid = threadIdx.x;
  const int lane = tid & 63;
  const int w = tid >> 6;
  const int m0 = blockIdx.y * 128;
  const int n0 = blockIdx.x * 128;

  // staging: each wave issues 2 A-insts + 2 B-insts of 1KB (64 lanes x 16B)
  const int srow = lane >> 2;          // 0..15 rows within inst
  const int scol = (lane & 3) * 8;     // k-offset (elements)
  const unsigned short* gA0 = A + (size_t)(m0 + (2 * w) * 16 + srow) * K + scol;
  const unsigned short* gA1 = A + (size_t)(m0 + (2 * w + 1) * 16 + srow) * K + scol;
  const unsigned short* gB0 = B + (size_t)(n0 + (2 * w) * 16 + srow) * K + scol;
  const unsigned short* gB1 = B + (size_t)(n0 + (2 * w + 1) * 16 + srow) * K + scol;
  unsigned short* lA0 = As + (2 * w) * 512;
  unsigned short* lA1 = As + (2 * w + 1) * 512;
  unsigned short* lB0 = Bs + (2 * w) * 512;
  unsigned short* lB1 = Bs + (2 * w + 1) * 512;

  const int wm = (w >> 1) * 64;
  const int wn = (w & 1) * 64;
  const int r16 = lane & 15;
  const int q8 = (lane >> 4) * 8;

  f32x4 acc[4][4] = {};

  for (int k0 = 0; k0 < K; k0 += 32) {
    ASYNC_COPY16(gA0 + k0, lA0);
    ASYNC_COPY16(gA1 + k0, lA1);
    ASYNC_COPY16(gB0 + k0, lB0);
    ASYNC_COPY16(gB1 + k0, lB1);
    __syncthreads();
    bf16x8 af[4], bq[4];
#pragma unroll
    for (int i = 0; i < 4; i++)
      af[i] = *(const bf16x8*)(As + (wm + i * 16 + r16) * 32 + q8);
#pragma unroll
    for (int j = 0; j < 4; j++)
      bq[j] = *(const bf16x8*)(Bs + (wn + j * 16 + r16) * 32 + q8);
#pragma unroll
    for (int i = 0; i < 4; i++)
#pragma unroll
      for (int j = 0; j < 4; j++)
        acc[i][j] = __builtin_amdgcn_mfma_f32_16x16x32_bf16(af[i], bq[j], acc[i][j], 0, 0, 0);
    __syncthreads();
  }

  // C/D layout: col = lane&15, row = (lane>>4)*4 + reg  [verified m89/m91]
  const int rbase = m0 + wm + (lane >> 4) * 4;
  const int cbase = n0 + wn + r16;
#pragma unroll
  for (int j = 0; j < 4; j++) {
    const int n = cbase + j * 16;
    const float bv = bias[n];
#pragma unroll
    for (int i = 0; i < 4; i++) {
#pragma unroll
      for (int r = 0; r < 4; r++) {
        const int m = rbase + i * 16 + r;
        float v = acc[i][j][r] + bv;
        if (RELU) v = fmaxf(v, 0.f);
        if (OUT_BF16) Cb[(size_t)m * N + n] = f2bf(v);
        else Cf[(size_t)m * N + n] = v;
      }
    }
  }
}

// =====================================================================
// attention: one block per (b,h). K staged bf16 in LDS, per-wave softmax,
// P staged bf16, V streamed from global (L1-resident). O = [B*S,512] bf16.
// =====================================================================
__global__ __launch_bounds__(256, 2) void attn_kernel(
    const unsigned short* __restrict__ qkv,  // [B*S,1536] bf16: q|k|v
    unsigned short* __restrict__ O) {        // [B*S,512]  bf16
  __shared__ unsigned short Kt[256 * 64];  // 32KB
  __shared__ unsigned short Qt[32 * 64];   // 4KB
  __shared__ unsigned short Pt[32 * 256];  // 16KB
  const int tid = threadIdx.x;
  const int lane = tid & 63;
  const int w = tid >> 6;
  const int b = blockIdx.x >> 3;
  const int h = blockIdx.x & 7;
  const unsigned short* base = qkv + (size_t)b * 256 * 1536;

  {  // stage K[256][64]
    const unsigned short* ksrc = base + 512 + h * 64;
    const int kr = tid >> 3;
    const int ch = (tid & 7) * 8;
#pragma unroll
    for (int rep = 0; rep < 8; rep++) {
      const int k = kr + rep * 32;
      *(uint4*)(Kt + k * 64 + ch) = *(const uint4*)(ksrc + (size_t)k * 1536 + ch);
    }
  }

  for (int qt = 0; qt < 8; qt++) {
    __syncthreads();  // Qt WAR vs previous tile's score phase (also covers K staging)
    {                 // stage Q tile [32][64]
      const int qr = tid >> 3;
      const int ch = (tid & 7) * 8;
      const unsigned short* qsrc = base + (size_t)(qt * 32 + qr) * 1536 + h * 64 + ch;
      *(uint4*)(Qt + qr * 64 + ch) = *(const uint4*)qsrc;
    }
    __syncthreads();

    // scores + softmax: wave w owns q-rows ql = w + 4r (no block barriers needed)
    for (int r = 0; r < 8; r++) {
      const int ql = w + 4 * r;
      float s0 = 0, s1 = 0, s2 = 0, s3 = 0;
#pragma unroll
      for (int j = 0; j < 32; j++) {
        const int d2 = (lane + j) & 31;  // rotation: bank-conflict-free
        const unsigned uq = *(const unsigned*)(Qt + ql * 64 + d2 * 2);
        const float q0 = bflo(uq), q1 = bfhi(uq);
        const unsigned k0v = *(const unsigned*)(Kt + (lane) * 64 + d2 * 2);
        const unsigned k1v = *(const unsigned*)(Kt + (lane + 64) * 64 + d2 * 2);
        const unsigned k2v = *(const unsigned*)(Kt + (lane + 128) * 64 + d2 * 2);
        const unsigned k3v = *(const unsigned*)(Kt + (lane + 192) * 64 + d2 * 2);
        s0 += q0 * bflo(k0v) + q1 * bfhi(k0v);
        s1 += q0 * bflo(k1v) + q1 * bfhi(k1v);
        s2 += q0 * bflo(k2v) + q1 * bfhi(k2v);
        s3 += q0 * bflo(k3v) + q1 * bfhi(k3v);
      }
      s0 *= 0.125f; s1 *= 0.125f; s2 *= 0.125f; s3 *= 0.125f;
      float m = fmaxf(fmaxf(s0, s1), fmaxf(s2, s3));
#pragma unroll
      for (int off = 32; off > 0; off >>= 1) m = fmaxf(m, __shfl_xor(m, off));
      float p0 = __expf(s0 - m), p1 = __expf(s1 - m);
      float p2 = __expf(s2 - m), p3 = __expf(s3 - m);
      float sum = p0 + p1 + p2 + p3;
#pragma unroll
      for (int off = 32; off > 0; off >>= 1) sum += __shfl_xor(sum, off);
      const float inv = 1.f / sum;
      Pt[ql * 256 + lane] = f2bf(p0 * inv);
      Pt[ql * 256 + lane + 64] = f2bf(p1 * inv);
      Pt[ql * 256 + lane + 128] = f2bf(p2 * inv);
      Pt[ql * 256 + lane + 192] = f2bf(p3 * inv);
    }

    // PV: each wave reads only its own Pt rows (no barrier needed).
    // lane = d; V[k,d] streamed coalesced from global.
    float acc[8] = {};
    const unsigned short* vp = base + 1024 + h * 64 + lane;
    for (int k = 0; k < 256; k += 2) {
      const float va = bf2f(vp[(size_t)k * 1536]);
      const float vb = bf2f(vp[(size_t)(k + 1) * 1536]);
#pragma unroll
      for (int r = 0; r < 8; r++) {
        const unsigned pu = *(const unsigned*)(Pt + (w + 4 * r) * 256 + k);
        acc[r] += bflo(pu) * va + bfhi(pu) * vb;
      }
    }
    unsigned short* op = O + (size_t)(b * 256 + qt * 32) * 512 + h * 64 + lane;
#pragma unroll
    for (int r = 0; r < 8; r++) op[(size_t)(w + 4 * r) * 512] = f2bf(acc[r]);
  }
}

// =====================================================================
// residual add + LayerNorm (biased var), writes fp32 master + bf16 copy
// =====================================================================
__global__ __launch_bounds__(256) void ln_kernel(
    float* __restrict__ x, const float* __restrict__ y,
    const float* __restrict__ g, const float* __restrict__ bb,
    unsigned short* __restrict__ xb) {
  const int row = blockIdx.x;
  const int tid = threadIdx.x;
  const size_t base = (size_t)row * 512;
  float v0 = x[base + tid] + y[base + tid];
  float v1 = x[base + tid + 256] + y[base + tid + 256];
  float s = v0 + v1, ss = v0 * v0 + v1 * v1;
#pragma unroll
  for (int off = 32; off > 0; off >>= 1) {
    s += __shfl_xor(s, off);
    ss += __shfl_xor(ss, off);
  }
  __shared__ float red[8];
  const int w = tid >> 6, lane = tid & 63;
  if (lane == 0) { red[w * 2] = s; red[w * 2 + 1] = ss; }
  __syncthreads();
  s = red[0] + red[2] + red[4] + red[6];
  ss = red[1] + red[3] + red[5] + red[7];
  const float mu = s * (1.f / 512.f);
  const float var = ss * (1.f / 512.f) - mu * mu;
  const float rs = rsqrtf(var + 1e-5f);
  const float o0 = (v0 - mu) * rs * g[tid] + bb[tid];
  const float o1 = (v1 - mu) * rs * g[tid + 256] + bb[tid + 256];
  x[base + tid] = o0;
  x[base + tid + 256] = o1;
  xb[base + tid] = f2bf(o0);
  xb[base + tid + 256] = f2bf(o1);
}

// =====================================================================
// latent: mem[64,256] += x[64,131072] . lat_w[256,131072]^T  (split-K fp32)
// grid (4 n-tiles, 128 k-chunks of 1024), 256 thr, 64x64 tile, atomics
// =====================================================================
__global__ void zero_kernel(float* __restrict__ p) {
  p[blockIdx.x * 256 + threadIdx.x] = 0.f;
}

__global__ __launch_bounds__(256) void latent_gemm(
    const float* __restrict__ X, const float* __restrict__ W,
    float* __restrict__ mem) {
  const int n0 = blockIdx.x * 64;
  const int kc0 = blockIdx.y * 1024;
  __shared__ float As[16][64];
  __shared__ float Bs[16][64];
  const int tid = threadIdx.x;
  const int lm = tid >> 2;
  const int lk = (tid & 3) * 4;
  const int tm = (tid >> 4) * 4;
  const int tn = (tid & 15) * 4;
  float c[4][4] = {};
  for (int kk = 0; kk < 1024; kk += 16) {
    const float4 av = *(const float4*)(X + (size_t)lm * 131072 + kc0 + kk + lk);
    const float4 bv = *(const float4*)(W + (size_t)(n0 + lm) * 131072 + kc0 + kk + lk);
    __syncthreads();
    As[lk + 0][lm] = av.x; As[lk + 1][lm] = av.y; As[lk + 2][lm] = av.z; As[lk + 3][lm] = av.w;
    Bs[lk + 0][lm] = bv.x; Bs[lk + 1][lm] = bv.y; Bs[lk + 2][lm] = bv.z; Bs[lk + 3][lm] = bv.w;
    __syncthreads();
#pragma unroll
    for (int t = 0; t < 16; t++) {
      float a[4], b[4];
#pragma unroll
      for (int i = 0; i < 4; i++) a[i] = As[t][tm + i];
#pragma unroll
      for (int j = 0; j < 4; j++) b[j] = Bs[t][tn + j];
#pragma unroll
      for (int i = 0; i < 4; i++)
#pragma unroll
        for (int j = 0; j < 4; j++) c[i][j] += a[i] * b[j];
    }
  }
#pragma unroll
  for (int i = 0; i < 4; i++)
#pragma unroll
    for (int j = 0; j < 4; j++)
      atomicAdd(&mem[(size_t)(tm + i) * 256 + n0 + tn + j], c[i][j]);
}

// =====================================================================
// head: pred[b] = sigmoid( sum_dl (mem[b,dl]+lat_b[dl])*head_w[dl] + head_b )
// =====================================================================
__global__ __launch_bounds__(256) void head_kernel(
    const float* __restrict__ mem, const float* __restrict__ lat_b,
    const float* __restrict__ head_w, const float* __restrict__ head_b,
    float* __restrict__ out) {
  const int b = blockIdx.x;
  const int tid = threadIdx.x;
  float v = (mem[(size_t)b * 256 + tid] + lat_b[tid]) * head_w[tid];
#pragma unroll
  for (int off = 32; off > 0; off >>= 1) v += __shfl_xor(v, off);
  __shared__ float red[4];
  const int w = tid >> 6, lane = tid & 63;
  if (lane == 0) red[w] = v;
  __syncthreads();
  if (tid == 0) {
    const float z = red[0] + red[1] + red[2] + red[3] + head_b[0];
    out[b] = 1.f / (1.f + __expf(-z));
  }
}

// =====================================================================
extern "C" void kernel_launch(void* const* d_in, const int* in_sizes, int n_in,
                              void* d_out, int out_size, void* d_ws, size_t ws_size,
                              hipStream_t stream) {
  (void)in_sizes; (void)n_in; (void)out_size; (void)ws_size;
  const float* src_pad = (const float*)d_in[0];
  const float* emb_w = (const float*)d_in[1];
  const float* emb_b = (const float*)d_in[2];
  const float* qkv_w = (const float*)d_in[3];
  const float* qkv_b = (const float*)d_in[4];
  const float* out_w = (const float*)d_in[5];
  const float* out_b = (const float*)d_in[6];
  const float* ff1_w = (const float*)d_in[7];
  const float* ff1_b = (const float*)d_in[8];
  const float* ff2_w = (const float*)d_in[9];
  const float* ff2_b = (const float*)d_in[10];
  const float* ln1_g = (const float*)d_in[11];
  const float* ln1_b = (const float*)d_in[12];
  const float* ln2_g = (const float*)d_in[13];
  const float* ln2_b = (const float*)d_in[14];
  const float* lat_w = (const float*)d_in[15];
  const float* lat_b = (const float*)d_in[16];
  const float* head_w = (const float*)d_in[17];
  const float* head_b = (const float*)d_in[18];
  float* out = (float*)d_out;

  // workspace layout (~222 MB)
  char* p = (char*)d_ws;
  float* x = (float*)p;             p += (size_t)16384 * 512 * 4;   // fp32 master
  unsigned short* xb = (unsigned short*)p; p += (size_t)16384 * 512 * 2;  // bf16 of x
  unsigned short* qkv = (unsigned short*)p;                         // [16384,1536] bf16
  float* y = (float*)qkv;           // fp32 [16384,512] aliases qkv (disjoint lifetimes)
  p += (size_t)16384 * 1536 * 2;
  unsigned short* attno = (unsigned short*)p; p += (size_t)16384 * 512 * 2;
  unsigned short* h = (unsigned short*)p;     p += (size_t)16384 * 2048 * 2;
  unsigned short* wq = (unsigned short*)p;    p += (size_t)4718592 * 2;
  unsigned short* wo = (unsigned short*)p;    p += (size_t)1572864 * 2;
  unsigned short* wf1 = (unsigned short*)p;   p += (size_t)6291456 * 2;
  unsigned short* wf2 = (unsigned short*)p;   p += (size_t)6291456 * 2;
  float* mem = (float*)p;           p += (size_t)16384 * 4;

  // weight conversion (ws is re-poisoned every call, so redo every call)
  cvt4_kernel<<<4608, 256, 0, stream>>>(qkv_w, wq);
  cvt4_kernel<<<1536, 256, 0, stream>>>(out_w, wo);
  cvt4_kernel<<<6144, 256, 0, stream>>>(ff1_w, wf1);
  cvt4_kernel<<<6144, 256, 0, stream>>>(ff2_w, wf2);

  embed_kernel<<<16384, 512, 0, stream>>>(src_pad, emb_w, emb_b, x, xb);

  for (int l = 0; l < 6; l++) {
    gemm_nt<0, 1><<<dim3(12, 128), 256, 0, stream>>>(
        xb, wq + (size_t)l * 786432, qkv_b + (size_t)l * 1536,
        nullptr, qkv, 16384, 1536, 512);
    attn_kernel<<<512, 256, 0, stream>>>(qkv, attno);
    gemm_nt<0, 0><<<dim3(4, 128), 256, 0, stream>>>(
        attno, wo + (size_t)l * 262144, out_b + (size_t)l * 512,
        y, nullptr, 16384, 512, 512);
    ln_kernel<<<16384, 256, 0, stream>>>(x, y, ln1_g + (size_t)l * 512,
                                         ln1_b + (size_t)l * 512, xb);
    gemm_nt<1, 1><<<dim3(16, 128), 256, 0, stream>>>(
        xb, wf1 + (size_t)l * 1048576, ff1_b + (size_t)l * 2048,
        nullptr, h, 16384, 2048, 512);
    gemm_nt<0, 0><<<dim3(4, 128), 256, 0, stream>>>(
        h, wf2 + (size_t)l * 1048576, ff2_b + (size_t)l * 512,
        y, nullptr, 16384, 512, 2048);
    ln_kernel<<<16384, 256, 0, stream>>>(x, y, ln2_g + (size_t)l * 512,
                                         ln2_b + (size_t)l * 512, xb);
  }

  zero_kernel<<<64, 256, 0, stream>>>(mem);
  latent_gemm<<<dim3(4, 128), 256, 0, stream>>>(x, lat_w, mem);
  head_kernel<<<64, 256, 0, stream>>>(mem, lat_b, head_w, head_b, out);
}

// Round 2
// 2086.490 us; speedup vs baseline: 2.8761x; 2.8761x over previous
//
#include <hip/hip_runtime.h>
#include <hip/hip_bf16.h>
#include <cstdint>

#define DEV static __device__ __forceinline__

typedef __attribute__((ext_vector_type(8))) short bf16x8;
typedef __attribute__((ext_vector_type(4))) float f32x4;

// ---------- bf16 helpers (bit-level) ----------
DEV unsigned short f2bf(float f) {
  union { float f; unsigned u; } c; c.f = f;
  unsigned u = c.u;
  return (unsigned short)((u + 0x7fffu + ((u >> 16) & 1u)) >> 16);  // RNE
}
DEV float bf2f(unsigned short h) {
  union { unsigned u; float f; } c; c.u = ((unsigned)h) << 16; return c.f;
}

// async global->LDS, 16B per lane; LDS dest is wave-uniform base + lane*16
#define ASYNC_COPY16(gsrc, ldst)                                                      \
  __builtin_amdgcn_global_load_lds(                                                   \
      (const __attribute__((address_space(1))) void*)(unsigned long long)(gsrc),      \
      (__attribute__((address_space(3))) void*)(unsigned int)(unsigned long long)(ldst), \
      16, 0, 0)

// =====================================================================
// fp32 -> bf16 weight conversion, 4 elems/thread
// =====================================================================
__global__ void cvt4_kernel(const float* __restrict__ s, unsigned short* __restrict__ d) {
  size_t i = ((size_t)blockIdx.x * 256 + threadIdx.x) * 4;
  float4 v = *(const float4*)(s + i);
  d[i + 0] = f2bf(v.x);
  d[i + 1] = f2bf(v.y);
  d[i + 2] = f2bf(v.z);
  d[i + 3] = f2bf(v.w);
}

// =====================================================================
// embedding + positional encoding: x[bs,d] (fp32 master + bf16 copy)
// =====================================================================
__global__ void embed_kernel(const float* __restrict__ src,    // [B*S,16]
                             const float* __restrict__ emb_w,  // [512,16]
                             const float* __restrict__ emb_b,  // [512]
                             float* __restrict__ x,
                             unsigned short* __restrict__ xb) {
  const int bs = blockIdx.x;        // 0..16383
  const int d = threadIdx.x;        // 0..511
  const int s = bs & 255;
  __shared__ float sv[16];
  if (d < 16) sv[d] = src[(size_t)bs * 16 + d];
  __syncthreads();
  const float* wr = emb_w + (size_t)d * 16;
  float acc = emb_b[d];
#pragma unroll
  for (int v = 0; v < 16; v++) acc += sv[v] * wr[v];
  const float den = __expf(-(float)(d & ~1) * (9.2103403719761836f / 512.f));
  const float arg = (float)s * den;
  acc += (d & 1) ? cosf(arg) : sinf(arg);
  x[(size_t)bs * 512 + d] = acc;
  xb[(size_t)bs * 512 + d] = f2bf(acc);
}

// =====================================================================
// bf16 MFMA GEMM, NT: C[m,n] = sum_k A[m,k]*B[n,k] + bias[n]
// 128x128 tile, BK=32, 256 threads (4 waves in 2x2), 4x4 MFMAs/wave
// =====================================================================
template <int RELU, int OUT_BF16>
__global__ __launch_bounds__(256, 2) void gemm_nt(
    const unsigned short* __restrict__ A,   // [M,K] bf16
    const unsigned short* __restrict__ B,   // [N,K] bf16
    const float* __restrict__ bias,         // [N]
    float* __restrict__ Cf,                 // [M,N] if !OUT_BF16
    unsigned short* __restrict__ Cb,        // [M,N] if OUT_BF16
    int M, int N, int K) {
  __shared__ unsigned short As[128 * 32];
  __shared__ unsigned short Bs[128 * 32];
  const int tid = threadIdx.x;
  const int lane = tid & 63;
  const int w = tid >> 6;
  const int m0 = blockIdx.y * 128;
  const int n0 = blockIdx.x * 128;

  const int srow = lane >> 2;          // 0..15 rows within inst
  const int scol = (lane & 3) * 8;     // k-offset (elements)
  const unsigned short* gA0 = A + (size_t)(m0 + (2 * w) * 16 + srow) * K + scol;
  const unsigned short* gA1 = A + (size_t)(m0 + (2 * w + 1) * 16 + srow) * K + scol;
  const unsigned short* gB0 = B + (size_t)(n0 + (2 * w) * 16 + srow) * K + scol;
  const unsigned short* gB1 = B + (size_t)(n0 + (2 * w + 1) * 16 + srow) * K + scol;
  unsigned short* lA0 = As + (2 * w) * 512;
  unsigned short* lA1 = As + (2 * w + 1) * 512;
  unsigned short* lB0 = Bs + (2 * w) * 512;
  unsigned short* lB1 = Bs + (2 * w + 1) * 512;

  const int wm = (w >> 1) * 64;
  const int wn = (w & 1) * 64;
  const int r16 = lane & 15;
  const int q8 = (lane >> 4) * 8;

  f32x4 acc[4][4] = {};

  for (int k0 = 0; k0 < K; k0 += 32) {
    ASYNC_COPY16(gA0 + k0, lA0);
    ASYNC_COPY16(gA1 + k0, lA1);
    ASYNC_COPY16(gB0 + k0, lB0);
    ASYNC_COPY16(gB1 + k0, lB1);
    __syncthreads();
    bf16x8 af[4], bq[4];
#pragma unroll
    for (int i = 0; i < 4; i++)
      af[i] = *(const bf16x8*)(As + (wm + i * 16 + r16) * 32 + q8);
#pragma unroll
    for (int j = 0; j < 4; j++)
      bq[j] = *(const bf16x8*)(Bs + (wn + j * 16 + r16) * 32 + q8);
#pragma unroll
    for (int i = 0; i < 4; i++)
#pragma unroll
      for (int j = 0; j < 4; j++)
        acc[i][j] = __builtin_amdgcn_mfma_f32_16x16x32_bf16(af[i], bq[j], acc[i][j], 0, 0, 0);
    __syncthreads();
  }

  const int rbase = m0 + wm + (lane >> 4) * 4;
  const int cbase = n0 + wn + r16;
#pragma unroll
  for (int j = 0; j < 4; j++) {
    const int n = cbase + j * 16;
    const float bv = bias[n];
#pragma unroll
    for (int i = 0; i < 4; i++) {
#pragma unroll
      for (int r = 0; r < 4; r++) {
        const int m = rbase + i * 16 + r;
        float v = acc[i][j][r] + bv;
        if (RELU) v = fmaxf(v, 0.f);
        if (OUT_BF16) Cb[(size_t)m * N + n] = f2bf(v);
        else Cf[(size_t)m * N + n] = v;
      }
    }
  }
}

// =====================================================================
// Attention kernel A: S = QK^T * scale, row-softmax, P (bf16) to global.
// Grid: 2048 = b(64) x h(8) x qt(4). 256 thr / 4 waves, wave = 16 q-rows.
// No LDS; Q/K frags straight from global (K slice is L1/L2-resident).
// =====================================================================
__global__ __launch_bounds__(256) void qk_kernel(
    const unsigned short* __restrict__ qkv,  // [B*S,1536]
    unsigned short* __restrict__ P) {        // [512,256,256]
  const int tid = threadIdx.x;
  const int lane = tid & 63;
  const int w = tid >> 6;
  const int r16 = lane & 15;
  const int quad = lane >> 4;
  const int qt = blockIdx.x & 3;
  const int h = (blockIdx.x >> 2) & 7;
  const int b = blockIdx.x >> 5;
  const int qbase = qt * 64 + w * 16;

  // A-frags of Q: A[m=r16][k=quad*8+j]
  const unsigned short* qrow =
      qkv + (size_t)(b * 256 + qbase + r16) * 1536 + h * 64 + quad * 8;
  const bf16x8 aQ0 = *(const bf16x8*)(qrow);
  const bf16x8 aQ1 = *(const bf16x8*)(qrow + 32);

  const unsigned short* krow =
      qkv + (size_t)(b * 256 + r16) * 1536 + 512 + h * 64 + quad * 8;

  f32x4 acc[16] = {};  // S[q=quad*4+r][k=j*16+r16]
#pragma unroll
  for (int j = 0; j < 16; j++) {
    const bf16x8 b0 = *(const bf16x8*)(krow + (size_t)j * 24576);
    const bf16x8 b1 = *(const bf16x8*)(krow + (size_t)j * 24576 + 32);
    acc[j] = __builtin_amdgcn_mfma_f32_16x16x32_bf16(aQ0, b0, acc[j], 0, 0, 0);
    acc[j] = __builtin_amdgcn_mfma_f32_16x16x32_bf16(aQ1, b1, acc[j], 0, 0, 0);
  }

  const size_t pbase = ((size_t)(b * 8 + h) * 256 + qbase + quad * 4) * 256;
#pragma unroll
  for (int r = 0; r < 4; r++) {
    float m = acc[0][r];
#pragma unroll
    for (int j = 1; j < 16; j++) m = fmaxf(m, acc[j][r]);
    m = fmaxf(m, __shfl_xor(m, 1));
    m = fmaxf(m, __shfl_xor(m, 2));
    m = fmaxf(m, __shfl_xor(m, 4));
    m = fmaxf(m, __shfl_xor(m, 8));
    m *= 0.125f;
    float p[16];
    float sum = 0.f;
#pragma unroll
    for (int j = 0; j < 16; j++) {
      p[j] = __expf(acc[j][r] * 0.125f - m);
      sum += p[j];
    }
    sum += __shfl_xor(sum, 1);
    sum += __shfl_xor(sum, 2);
    sum += __shfl_xor(sum, 4);
    sum += __shfl_xor(sum, 8);
    const float inv = 1.f / sum;
#pragma unroll
    for (int j = 0; j < 16; j++) {
      const unsigned v16 = f2bf(p[j] * inv);
      const unsigned pr = (unsigned)__shfl_xor((int)v16, 1);
      if (!(r16 & 1))
        *(unsigned*)(P + pbase + (size_t)r * 256 + j * 16 + r16) =
            (v16 & 0xffffu) | (pr << 16);
    }
  }
}

// =====================================================================
// Attention kernel B: O = P.V per (b,h,qt). V^T staged in LDS (33KB,
// conflict-free packed-pair writes), P A-frags from global, 32 MFMAs/wave.
// =====================================================================
__global__ __launch_bounds__(256) void pv_kernel(
    const unsigned short* __restrict__ qkv,
    const unsigned short* __restrict__ P,
    unsigned short* __restrict__ O) {  // [B*S,512] bf16
  __shared__ unsigned short Vt[64 * 264];  // Vt[d][k], row stride 264
  const int tid = threadIdx.x;
  const int lane = tid & 63;
  const int w = tid >> 6;
  const int r16 = lane & 15;
  const int quad = lane >> 4;
  const int qt = blockIdx.x & 3;
  const int h = (blockIdx.x >> 2) & 7;
  const int b = blockIdx.x >> 5;

  // stage V^T: kp in 0..127 per wave-quadrant, k0 = 2*kp
  {
    const int kp = w * 32 + (lane & 31);
    const int dhalf = lane >> 5;
    const unsigned short* vbase =
        qkv + (size_t)(b * 256 + 2 * kp) * 1536 + 1024 + h * 64;
    unsigned* dst = (unsigned*)Vt;
#pragma unroll
    for (int t = 0; t < 4; t++) {
      const int dc = dhalf + 2 * t;  // d-chunk 0..7
      const uint4 a = *(const uint4*)(vbase + dc * 8);
      const uint4 bb = *(const uint4*)(vbase + 1536 + dc * 8);
      const unsigned* ap = (const unsigned*)&a;
      const unsigned* bp = (const unsigned*)&bb;
#pragma unroll
      for (int i = 0; i < 4; i++) {
        const unsigned lo = ap[i], hi = bp[i];
        dst[(dc * 8 + 2 * i) * 132 + kp] = (lo & 0xffffu) | (hi << 16);
        dst[(dc * 8 + 2 * i + 1) * 132 + kp] = (lo >> 16) | (hi & 0xffff0000u);
      }
    }
  }
  __syncthreads();

  const int qbase = qt * 64 + w * 16;
  const unsigned short* prow =
      P + ((size_t)(b * 8 + h) * 256 + qbase + r16) * 256 + quad * 8;
  f32x4 oacc[4] = {};
#pragma unroll
  for (int s = 0; s < 8; s++) {
    const bf16x8 aP = *(const bf16x8*)(prow + s * 32);
#pragma unroll
    for (int t = 0; t < 4; t++) {
      const bf16x8 bV = *(const bf16x8*)(Vt + (t * 16 + r16) * 264 + s * 32 + quad * 8);
      oacc[t] = __builtin_amdgcn_mfma_f32_16x16x32_bf16(aP, bV, oacc[t], 0, 0, 0);
    }
  }

  const size_t obase = (size_t)(b * 256 + qbase + quad * 4) * 512 + h * 64;
#pragma unroll
  for (int t = 0; t < 4; t++) {
#pragma unroll
    for (int r = 0; r < 4; r++) {
      const unsigned v16 = f2bf(oacc[t][r]);
      const unsigned pr = (unsigned)__shfl_xor((int)v16, 1);
      if (!(r16 & 1))
        *(unsigned*)(O + obase + (size_t)r * 512 + t * 16 + r16) =
            (v16 & 0xffffu) | (pr << 16);
    }
  }
}

// =====================================================================
// residual add + LayerNorm (biased var), writes fp32 master + bf16 copy
// =====================================================================
__global__ __launch_bounds__(256) void ln_kernel(
    float* __restrict__ x, const float* __restrict__ y,
    const float* __restrict__ g, const float* __restrict__ bb,
    unsigned short* __restrict__ xb) {
  const int row = blockIdx.x;
  const int tid = threadIdx.x;
  const size_t base = (size_t)row * 512;
  float v0 = x[base + tid] + y[base + tid];
  float v1 = x[base + tid + 256] + y[base + tid + 256];
  float s = v0 + v1, ss = v0 * v0 + v1 * v1;
#pragma unroll
  for (int off = 32; off > 0; off >>= 1) {
    s += __shfl_xor(s, off);
    ss += __shfl_xor(ss, off);
  }
  __shared__ float red[8];
  const int w = tid >> 6, lane = tid & 63;
  if (lane == 0) { red[w * 2] = s; red[w * 2 + 1] = ss; }
  __syncthreads();
  s = red[0] + red[2] + red[4] + red[6];
  ss = red[1] + red[3] + red[5] + red[7];
  const float mu = s * (1.f / 512.f);
  const float var = ss * (1.f / 512.f) - mu * mu;
  const float rs = rsqrtf(var + 1e-5f);
  const float o0 = (v0 - mu) * rs * g[tid] + bb[tid];
  const float o1 = (v1 - mu) * rs * g[tid + 256] + bb[tid + 256];
  x[base + tid] = o0;
  x[base + tid + 256] = o1;
  xb[base + tid] = f2bf(o0);
  xb[base + tid + 256] = f2bf(o1);
}

// =====================================================================
// latent: mem[64,256] += x[64,131072] . lat_w[256,131072]^T  (split-K fp32)
// =====================================================================
__global__ void zero_kernel(float* __restrict__ p) {
  p[blockIdx.x * 256 + threadIdx.x] = 0.f;
}

__global__ __launch_bounds__(256) void latent_gemm(
    const float* __restrict__ X, const float* __restrict__ W,
    float* __restrict__ mem) {
  const int n0 = blockIdx.x * 64;
  const int kc0 = blockIdx.y * 1024;
  __shared__ float As[16][64];
  __shared__ float Bs[16][64];
  const int tid = threadIdx.x;
  const int lm = tid >> 2;
  const int lk = (tid & 3) * 4;
  const int tm = (tid >> 4) * 4;
  const int tn = (tid & 15) * 4;
  float c[4][4] = {};
  for (int kk = 0; kk < 1024; kk += 16) {
    const float4 av = *(const float4*)(X + (size_t)lm * 131072 + kc0 + kk + lk);
    const float4 bv = *(const float4*)(W + (size_t)(n0 + lm) * 131072 + kc0 + kk + lk);
    __syncthreads();
    As[lk + 0][lm] = av.x; As[lk + 1][lm] = av.y; As[lk + 2][lm] = av.z; As[lk + 3][lm] = av.w;
    Bs[lk + 0][lm] = bv.x; Bs[lk + 1][lm] = bv.y; Bs[lk + 2][lm] = bv.z; Bs[lk + 3][lm] = bv.w;
    __syncthreads();
#pragma unroll
    for (int t = 0; t < 16; t++) {
      float a[4], b[4];
#pragma unroll
      for (int i = 0; i < 4; i++) a[i] = As[t][tm + i];
#pragma unroll
      for (int j = 0; j < 4; j++) b[j] = Bs[t][tn + j];
#pragma unroll
      for (int i = 0; i < 4; i++)
#pragma unroll
        for (int j = 0; j < 4; j++) c[i][j] += a[i] * b[j];
    }
  }
#pragma unroll
  for (int i = 0; i < 4; i++)
#pragma unroll
    for (int j = 0; j < 4; j++)
      atomicAdd(&mem[(size_t)(tm + i) * 256 + n0 + tn + j], c[i][j]);
}

// =====================================================================
__global__ __launch_bounds__(256) void head_kernel(
    const float* __restrict__ mem, const float* __restrict__ lat_b,
    const float* __restrict__ head_w, const float* __restrict__ head_b,
    float* __restrict__ out) {
  const int b = blockIdx.x;
  const int tid = threadIdx.x;
  float v = (mem[(size_t)b * 256 + tid] + lat_b[tid]) * head_w[tid];
#pragma unroll
  for (int off = 32; off > 0; off >>= 1) v += __shfl_xor(v, off);
  __shared__ float red[4];
  const int w = tid >> 6, lane = tid & 63;
  if (lane == 0) red[w] = v;
  __syncthreads();
  if (tid == 0) {
    const float z = red[0] + red[1] + red[2] + red[3] + head_b[0];
    out[b] = 1.f / (1.f + __expf(-z));
  }
}

// =====================================================================
extern "C" void kernel_launch(void* const* d_in, const int* in_sizes, int n_in,
                              void* d_out, int out_size, void* d_ws, size_t ws_size,
                              hipStream_t stream) {
  (void)in_sizes; (void)n_in; (void)out_size; (void)ws_size;
  const float* src_pad = (const float*)d_in[0];
  const float* emb_w = (const float*)d_in[1];
  const float* emb_b = (const float*)d_in[2];
  const float* qkv_w = (const float*)d_in[3];
  const float* qkv_b = (const float*)d_in[4];
  const float* out_w = (const float*)d_in[5];
  const float* out_b = (const float*)d_in[6];
  const float* ff1_w = (const float*)d_in[7];
  const float* ff1_b = (const float*)d_in[8];
  const float* ff2_w = (const float*)d_in[9];
  const float* ff2_b = (const float*)d_in[10];
  const float* ln1_g = (const float*)d_in[11];
  const float* ln1_b = (const float*)d_in[12];
  const float* ln2_g = (const float*)d_in[13];
  const float* ln2_b = (const float*)d_in[14];
  const float* lat_w = (const float*)d_in[15];
  const float* lat_b = (const float*)d_in[16];
  const float* head_w = (const float*)d_in[17];
  const float* head_b = (const float*)d_in[18];
  float* out = (float*)d_out;

  // workspace layout (~213 MB)
  char* p = (char*)d_ws;
  float* x = (float*)p;             p += (size_t)16384 * 512 * 4;   // fp32 master
  unsigned short* xb = (unsigned short*)p; p += (size_t)16384 * 512 * 2;  // bf16 of x
  unsigned short* qkv = (unsigned short*)p;                         // [16384,1536] bf16
  float* y = (float*)qkv;           // fp32 [16384,512] aliases qkv (disjoint lifetimes)
  p += (size_t)16384 * 1536 * 2;
  unsigned short* attno = (unsigned short*)p; p += (size_t)16384 * 512 * 2;
  unsigned short* h = (unsigned short*)p;     p += (size_t)16384 * 2048 * 2;
  unsigned short* P = h;            // [512,256,256] bf16 aliases h (disjoint lifetimes)
  unsigned short* wq = (unsigned short*)p;    p += (size_t)4718592 * 2;
  unsigned short* wo = (unsigned short*)p;    p += (size_t)1572864 * 2;
  unsigned short* wf1 = (unsigned short*)p;   p += (size_t)6291456 * 2;
  unsigned short* wf2 = (unsigned short*)p;   p += (size_t)6291456 * 2;
  float* mem = (float*)p;           p += (size_t)16384 * 4;

  cvt4_kernel<<<4608, 256, 0, stream>>>(qkv_w, wq);
  cvt4_kernel<<<1536, 256, 0, stream>>>(out_w, wo);
  cvt4_kernel<<<6144, 256, 0, stream>>>(ff1_w, wf1);
  cvt4_kernel<<<6144, 256, 0, stream>>>(ff2_w, wf2);

  embed_kernel<<<16384, 512, 0, stream>>>(src_pad, emb_w, emb_b, x, xb);

  for (int l = 0; l < 6; l++) {
    gemm_nt<0, 1><<<dim3(12, 128), 256, 0, stream>>>(
        xb, wq + (size_t)l * 786432, qkv_b + (size_t)l * 1536,
        nullptr, qkv, 16384, 1536, 512);
    qk_kernel<<<2048, 256, 0, stream>>>(qkv, P);
    pv_kernel<<<2048, 256, 0, stream>>>(qkv, P, attno);
    gemm_nt<0, 0><<<dim3(4, 128), 256, 0, stream>>>(
        attno, wo + (size_t)l * 262144, out_b + (size_t)l * 512,
        y, nullptr, 16384, 512, 512);
    ln_kernel<<<16384, 256, 0, stream>>>(x, y, ln1_g + (size_t)l * 512,
                                         ln1_b + (size_t)l * 512, xb);
    gemm_nt<1, 1><<<dim3(16, 128), 256, 0, stream>>>(
        xb, wf1 + (size_t)l * 1048576, ff1_b + (size_t)l * 2048,
        nullptr, h, 16384, 2048, 512);
    gemm_nt<0, 0><<<dim3(4, 128), 256, 0, stream>>>(
        h, wf2 + (size_t)l * 1048576, ff2_b + (size_t)l * 512,
        y, nullptr, 16384, 512, 2048);
    ln_kernel<<<16384, 256, 0, stream>>>(x, y, ln2_g + (size_t)l * 512,
                                         ln2_b + (size_t)l * 512, xb);
  }

  zero_kernel<<<64, 256, 0, stream>>>(mem);
  latent_gemm<<<dim3(4, 128), 256, 0, stream>>>(x, lat_w, mem);
  head_kernel<<<64, 256, 0, stream>>>(mem, lat_b, head_w, head_b, out);
}

// Round 3
// 2060.110 us; speedup vs baseline: 2.9129x; 1.0128x over previous
//
#include <hip/hip_runtime.h>
#include <hip/hip_bf16.h>
#include <cstdint>

#define DEV static __device__ __forceinline__

typedef __attribute__((ext_vector_type(8))) short bf16x8;
typedef __attribute__((ext_vector_type(4))) float f32x4;

// ---------- bf16 helpers (bit-level) ----------
DEV unsigned short f2bf(float f) {
  union { float f; unsigned u; } c; c.f = f;
  unsigned u = c.u;
  return (unsigned short)((u + 0x7fffu + ((u >> 16) & 1u)) >> 16);  // RNE
}
DEV float bf2f(unsigned short h) {
  union { unsigned u; float f; } c; c.u = ((unsigned)h) << 16; return c.f;
}
// fast round-half-up bf16 pair pack: lo16 = bf(a), hi16 = bf(b), 3 VALU ops
DEV unsigned pack_bf16(float a, float b) {
  union { float f; unsigned u; } ca, cb; ca.f = a; cb.f = b;
  return __builtin_amdgcn_perm(cb.u + 0x8000u, ca.u + 0x8000u, 0x07060302u);
}

// async global->LDS, 16B per lane; LDS dest is wave-uniform base + lane*16
#define ASYNC_COPY16(gsrc, ldst)                                                      \
  __builtin_amdgcn_global_load_lds(                                                   \
      (const __attribute__((address_space(1))) void*)(unsigned long long)(gsrc),      \
      (__attribute__((address_space(3))) void*)(unsigned int)(unsigned long long)(ldst), \
      16, 0, 0)

// =====================================================================
// fp32 -> bf16 weight conversion, 4 elems/thread
// =====================================================================
__global__ void cvt4_kernel(const float* __restrict__ s, unsigned short* __restrict__ d) {
  size_t i = ((size_t)blockIdx.x * 256 + threadIdx.x) * 4;
  float4 v = *(const float4*)(s + i);
  d[i + 0] = f2bf(v.x);
  d[i + 1] = f2bf(v.y);
  d[i + 2] = f2bf(v.z);
  d[i + 3] = f2bf(v.w);
}

// =====================================================================
// embedding + positional encoding: x[bs,d] (fp32 master + bf16 copy)
// =====================================================================
__global__ void embed_kernel(const float* __restrict__ src,    // [B*S,16]
                             const float* __restrict__ emb_w,  // [512,16]
                             const float* __restrict__ emb_b,  // [512]
                             float* __restrict__ x,
                             unsigned short* __restrict__ xb) {
  const int bs = blockIdx.x;        // 0..16383
  const int d = threadIdx.x;        // 0..511
  const int s = bs & 255;
  __shared__ float sv[16];
  if (d < 16) sv[d] = src[(size_t)bs * 16 + d];
  __syncthreads();
  const float* wr = emb_w + (size_t)d * 16;
  float acc = emb_b[d];
#pragma unroll
  for (int v = 0; v < 16; v++) acc += sv[v] * wr[v];
  const float den = __expf(-(float)(d & ~1) * (9.2103403719761836f / 512.f));
  const float arg = (float)s * den;
  acc += (d & 1) ? __cosf(arg) : __sinf(arg);
  x[(size_t)bs * 512 + d] = acc;
  xb[(size_t)bs * 512 + d] = f2bf(acc);
}

// =====================================================================
// bf16 MFMA GEMM, NT: C[m,n] = sum_k A[m,k]*B[n,k] + bias[n] (+res[m,n])
// 128x128 tile, BK=32, 256 threads (4 waves in 2x2), 4x4 MFMAs/wave
// =====================================================================
template <int RELU, int OUT_BF16, int ADD_RES>
__global__ __launch_bounds__(256, 2) void gemm_nt(
    const unsigned short* __restrict__ A,   // [M,K] bf16
    const unsigned short* __restrict__ B,   // [N,K] bf16
    const float* __restrict__ bias,         // [N]
    const float* __restrict__ res,          // [M,N] fp32 residual (if ADD_RES)
    float* __restrict__ Cf,                 // [M,N] if !OUT_BF16
    unsigned short* __restrict__ Cb,        // [M,N] if OUT_BF16
    int M, int N, int K) {
  __shared__ unsigned short As[128 * 32];
  __shared__ unsigned short Bs[128 * 32];
  const int tid = threadIdx.x;
  const int lane = tid & 63;
  const int w = tid >> 6;
  const int m0 = blockIdx.y * 128;
  const int n0 = blockIdx.x * 128;

  const int srow = lane >> 2;          // 0..15 rows within inst
  const int scol = (lane & 3) * 8;     // k-offset (elements)
  const unsigned short* gA0 = A + (size_t)(m0 + (2 * w) * 16 + srow) * K + scol;
  const unsigned short* gA1 = A + (size_t)(m0 + (2 * w + 1) * 16 + srow) * K + scol;
  const unsigned short* gB0 = B + (size_t)(n0 + (2 * w) * 16 + srow) * K + scol;
  const unsigned short* gB1 = B + (size_t)(n0 + (2 * w + 1) * 16 + srow) * K + scol;
  unsigned short* lA0 = As + (2 * w) * 512;
  unsigned short* lA1 = As + (2 * w + 1) * 512;
  unsigned short* lB0 = Bs + (2 * w) * 512;
  unsigned short* lB1 = Bs + (2 * w + 1) * 512;

  const int wm = (w >> 1) * 64;
  const int wn = (w & 1) * 64;
  const int r16 = lane & 15;
  const int q8 = (lane >> 4) * 8;

  f32x4 acc[4][4] = {};

  for (int k0 = 0; k0 < K; k0 += 32) {
    ASYNC_COPY16(gA0 + k0, lA0);
    ASYNC_COPY16(gA1 + k0, lA1);
    ASYNC_COPY16(gB0 + k0, lB0);
    ASYNC_COPY16(gB1 + k0, lB1);
    __syncthreads();
    bf16x8 af[4], bq[4];
#pragma unroll
    for (int i = 0; i < 4; i++)
      af[i] = *(const bf16x8*)(As + (wm + i * 16 + r16) * 32 + q8);
#pragma unroll
    for (int j = 0; j < 4; j++)
      bq[j] = *(const bf16x8*)(Bs + (wn + j * 16 + r16) * 32 + q8);
#pragma unroll
    for (int i = 0; i < 4; i++)
#pragma unroll
      for (int j = 0; j < 4; j++)
        acc[i][j] = __builtin_amdgcn_mfma_f32_16x16x32_bf16(af[i], bq[j], acc[i][j], 0, 0, 0);
    __syncthreads();
  }

  const int rbase = m0 + wm + (lane >> 4) * 4;
  const int cbase = n0 + wn + r16;
#pragma unroll
  for (int j = 0; j < 4; j++) {
    const int n = cbase + j * 16;
    const float bv = bias[n];
#pragma unroll
    for (int i = 0; i < 4; i++) {
#pragma unroll
      for (int r = 0; r < 4; r++) {
        const int m = rbase + i * 16 + r;
        float v = acc[i][j][r] + bv;
        if (ADD_RES) v += res[(size_t)m * N + n];
        if (RELU) v = fmaxf(v, 0.f);
        if (OUT_BF16) Cb[(size_t)m * N + n] = f2bf(v);
        else Cf[(size_t)m * N + n] = v;
      }
    }
  }
}

// =====================================================================
// Attention A: S^T = K.Q^T (A=K rows, B=Q rows) -> in-register softmax
// over k (rows of S^T, = quad lanes x regs) -> P[q][k] bf16 to global.
// Lane holds S^T[k=t*16+quad*4+reg][q=r16]; packs 4 consecutive k -> uint2.
// Grid 2048 = b(64) x h(8) x qt(4); 4 waves x 16 q-rows.
// =====================================================================
__global__ __launch_bounds__(256) void qk_kernel(
    const unsigned short* __restrict__ qkv,  // [B*S,1536]
    unsigned short* __restrict__ P) {        // [512,256,256]
  const int tid = threadIdx.x;
  const int lane = tid & 63;
  const int w = tid >> 6;
  const int r16 = lane & 15;
  const int quad = lane >> 4;
  const int qt = blockIdx.x & 3;
  const int h = (blockIdx.x >> 2) & 7;
  const int b = blockIdx.x >> 5;
  const int qbase = qt * 64 + w * 16;

  // B-frag: Q row (qbase + r16)
  const unsigned short* qrow =
      qkv + (size_t)(b * 256 + qbase + r16) * 1536 + h * 64 + quad * 8;
  const bf16x8 bQ0 = *(const bf16x8*)(qrow);
  const bf16x8 bQ1 = *(const bf16x8*)(qrow + 32);

  // A-frag: K rows (t*16 + r16)
  const unsigned short* krow =
      qkv + (size_t)(b * 256 + r16) * 1536 + 512 + h * 64 + quad * 8;

  f32x4 acc[16] = {};  // S^T[k = t*16+quad*4+reg][q = r16]
#pragma unroll
  for (int t = 0; t < 16; t++) {
    const bf16x8 aK0 = *(const bf16x8*)(krow + (size_t)t * 24576);
    const bf16x8 aK1 = *(const bf16x8*)(krow + (size_t)t * 24576 + 32);
    acc[t] = __builtin_amdgcn_mfma_f32_16x16x32_bf16(aK0, bQ0, acc[t], 0, 0, 0);
    acc[t] = __builtin_amdgcn_mfma_f32_16x16x32_bf16(aK1, bQ1, acc[t], 0, 0, 0);
  }

  // softmax over k for fixed q=r16: regs + tiles in-lane, quad via shfl 16/32
  float mx = acc[0][0];
#pragma unroll
  for (int t = 0; t < 16; t++)
#pragma unroll
    for (int r = 0; r < 4; r++) mx = fmaxf(mx, acc[t][r]);
  mx = fmaxf(mx, __shfl_xor(mx, 16));
  mx = fmaxf(mx, __shfl_xor(mx, 32));
  float sum = 0.f;
#pragma unroll
  for (int t = 0; t < 16; t++)
#pragma unroll
    for (int r = 0; r < 4; r++) {
      acc[t][r] = __expf((acc[t][r] - mx) * 0.125f);
      sum += acc[t][r];
    }
  sum += __shfl_xor(sum, 16);
  sum += __shfl_xor(sum, 32);
  const float inv = 1.f / sum;

  unsigned short* prow =
      P + ((size_t)(b * 8 + h) * 256 + qbase + r16) * 256 + quad * 4;
#pragma unroll
  for (int t = 0; t < 16; t++) {
    uint2 u;
    u.x = pack_bf16(acc[t][0] * inv, acc[t][1] * inv);
    u.y = pack_bf16(acc[t][2] * inv, acc[t][3] * inv);
    *(uint2*)(prow + t * 16) = u;
  }
}

// =====================================================================
// Attention B: O^T = V^T.P (A=Vt from LDS, B=P rows from global).
// Lane holds O^T[d=t*16+quad*4+reg][q=r16] -> uint2 packed store.
// =====================================================================
__global__ __launch_bounds__(256) void pv_kernel(
    const unsigned short* __restrict__ qkv,
    const unsigned short* __restrict__ P,
    unsigned short* __restrict__ O) {  // [B*S,512] bf16
  __shared__ unsigned short Vt[64 * 264];  // Vt[d][k], row stride 264
  const int tid = threadIdx.x;
  const int lane = tid & 63;
  const int w = tid >> 6;
  const int r16 = lane & 15;
  const int quad = lane >> 4;
  const int qt = blockIdx.x & 3;
  const int h = (blockIdx.x >> 2) & 7;
  const int b = blockIdx.x >> 5;

  // stage V^T (verified round-2 pattern)
  {
    const int kp = w * 32 + (lane & 31);
    const int dhalf = lane >> 5;
    const unsigned short* vbase =
        qkv + (size_t)(b * 256 + 2 * kp) * 1536 + 1024 + h * 64;
    unsigned* dst = (unsigned*)Vt;
#pragma unroll
    for (int t = 0; t < 4; t++) {
      const int dc = dhalf + 2 * t;  // d-chunk 0..7
      const uint4 a = *(const uint4*)(vbase + dc * 8);
      const uint4 bb = *(const uint4*)(vbase + 1536 + dc * 8);
      const unsigned* ap = (const unsigned*)&a;
      const unsigned* bp = (const unsigned*)&bb;
#pragma unroll
      for (int i = 0; i < 4; i++) {
        const unsigned lo = ap[i], hi = bp[i];
        dst[(dc * 8 + 2 * i) * 132 + kp] = (lo & 0xffffu) | (hi << 16);
        dst[(dc * 8 + 2 * i + 1) * 132 + kp] = (lo >> 16) | (hi & 0xffff0000u);
      }
    }
  }
  __syncthreads();

  const int qbase = qt * 64 + w * 16;
  const unsigned short* prow =
      P + ((size_t)(b * 8 + h) * 256 + qbase + r16) * 256 + quad * 8;
  f32x4 o[4] = {};  // O^T[d-tile t][q=r16]
#pragma unroll
  for (int s = 0; s < 8; s++) {
    const bf16x8 bP = *(const bf16x8*)(prow + s * 32);
#pragma unroll
    for (int t = 0; t < 4; t++) {
      const bf16x8 aV = *(const bf16x8*)(Vt + (t * 16 + r16) * 264 + s * 32 + quad * 8);
      o[t] = __builtin_amdgcn_mfma_f32_16x16x32_bf16(aV, bP, o[t], 0, 0, 0);
    }
  }

  unsigned short* orow =
      O + (size_t)(b * 256 + qbase + r16) * 512 + h * 64 + quad * 4;
#pragma unroll
  for (int t = 0; t < 4; t++) {
    uint2 u;
    u.x = pack_bf16(o[t][0], o[t][1]);
    u.y = pack_bf16(o[t][2], o[t][3]);
    *(uint2*)(orow + t * 16) = u;
  }
}

// =====================================================================
// LayerNorm over z (residual already fused into GEMM epilogue):
// reads z fp32, writes x fp32 + xb bf16
// =====================================================================
__global__ __launch_bounds__(256) void ln_kernel(
    const float* __restrict__ z, const float* __restrict__ g,
    const float* __restrict__ bb, float* __restrict__ x,
    unsigned short* __restrict__ xb) {
  const int row = blockIdx.x;
  const int tid = threadIdx.x;
  const size_t base = (size_t)row * 512;
  float v0 = z[base + tid];
  float v1 = z[base + tid + 256];
  float s = v0 + v1, ss = v0 * v0 + v1 * v1;
#pragma unroll
  for (int off = 32; off > 0; off >>= 1) {
    s += __shfl_xor(s, off);
    ss += __shfl_xor(ss, off);
  }
  __shared__ float red[8];
  const int w = tid >> 6, lane = tid & 63;
  if (lane == 0) { red[w * 2] = s; red[w * 2 + 1] = ss; }
  __syncthreads();
  s = red[0] + red[2] + red[4] + red[6];
  ss = red[1] + red[3] + red[5] + red[7];
  const float mu = s * (1.f / 512.f);
  const float var = ss * (1.f / 512.f) - mu * mu;
  const float rs = rsqrtf(var + 1e-5f);
  const float o0 = (v0 - mu) * rs * g[tid] + bb[tid];
  const float o1 = (v1 - mu) * rs * g[tid + 256] + bb[tid + 256];
  x[base + tid] = o0;
  x[base + tid + 256] = o1;
  xb[base + tid] = f2bf(o0);
  xb[base + tid + 256] = f2bf(o1);
}

// =====================================================================
// latent: mem[64,256] += xb[64,131072](bf16) . W[256,131072]^T
// bf16 MFMA streaming, W converted fp32->bf16 in-flight, split-K atomics.
// grid (4 n-blocks of 64, 128 k-chunks of 1024), 256 thr / 4 waves.
// =====================================================================
__global__ void zero_kernel(float* __restrict__ p) {
  p[blockIdx.x * 256 + threadIdx.x] = 0.f;
}

__global__ __launch_bounds__(256) void latent_gemm(
    const unsigned short* __restrict__ xb, const float* __restrict__ W,
    float* __restrict__ mem) {
  const int tid = threadIdx.x;
  const int lane = tid & 63;
  const int w = tid >> 6;
  const int r16 = lane & 15;
  const int quad = lane >> 4;
  const int n0 = blockIdx.x * 64 + w * 16;     // wave's 16 n-rows
  const int kc0 = blockIdx.y * 1024;

  const float* wrow = W + (size_t)(n0 + r16) * 131072 + kc0 + quad * 8;
  const unsigned short* xrow = xb + (size_t)r16 * 131072 + kc0 + quad * 8;

  f32x4 c[4] = {};  // C[b = i*16+quad*4+reg][n = n0+r16]
  for (int k = 0; k < 1024; k += 32) {
    const float4 wa = *(const float4*)(wrow + k);
    const float4 wb = *(const float4*)(wrow + k + 4);
    union { unsigned u[4]; bf16x8 v; } cw;
    cw.u[0] = pack_bf16(wa.x, wa.y);
    cw.u[1] = pack_bf16(wa.z, wa.w);
    cw.u[2] = pack_bf16(wb.x, wb.y);
    cw.u[3] = pack_bf16(wb.z, wb.w);
#pragma unroll
    for (int i = 0; i < 4; i++) {
      const bf16x8 aX = *(const bf16x8*)(xrow + (size_t)i * 2097152 + k);
      c[i] = __builtin_amdgcn_mfma_f32_16x16x32_bf16(aX, cw.v, c[i], 0, 0, 0);
    }
  }
#pragma unroll
  for (int i = 0; i < 4; i++)
#pragma unroll
    for (int r = 0; r < 4; r++)
      atomicAdd(&mem[(size_t)(i * 16 + quad * 4 + r) * 256 + n0 + r16], c[i][r]);
}

// =====================================================================
__global__ __launch_bounds__(256) void head_kernel(
    const float* __restrict__ mem, const float* __restrict__ lat_b,
    const float* __restrict__ head_w, const float* __restrict__ head_b,
    float* __restrict__ out) {
  const int b = blockIdx.x;
  const int tid = threadIdx.x;
  float v = (mem[(size_t)b * 256 + tid] + lat_b[tid]) * head_w[tid];
#pragma unroll
  for (int off = 32; off > 0; off >>= 1) v += __shfl_xor(v, off);
  __shared__ float red[4];
  const int w = tid >> 6, lane = tid & 63;
  if (lane == 0) red[w] = v;
  __syncthreads();
  if (tid == 0) {
    const float z = red[0] + red[1] + red[2] + red[3] + head_b[0];
    out[b] = 1.f / (1.f + __expf(-z));
  }
}

// =====================================================================
extern "C" void kernel_launch(void* const* d_in, const int* in_sizes, int n_in,
                              void* d_out, int out_size, void* d_ws, size_t ws_size,
                              hipStream_t stream) {
  (void)in_sizes; (void)n_in; (void)out_size; (void)ws_size;
  const float* src_pad = (const float*)d_in[0];
  const float* emb_w = (const float*)d_in[1];
  const float* emb_b = (const float*)d_in[2];
  const float* qkv_w = (const float*)d_in[3];
  const float* qkv_b = (const float*)d_in[4];
  const float* out_w = (const float*)d_in[5];
  const float* out_b = (const float*)d_in[6];
  const float* ff1_w = (const float*)d_in[7];
  const float* ff1_b = (const float*)d_in[8];
  const float* ff2_w = (const float*)d_in[9];
  const float* ff2_b = (const float*)d_in[10];
  const float* ln1_g = (const float*)d_in[11];
  const float* ln1_b = (const float*)d_in[12];
  const float* ln2_g = (const float*)d_in[13];
  const float* ln2_b = (const float*)d_in[14];
  const float* lat_w = (const float*)d_in[15];
  const float* lat_b = (const float*)d_in[16];
  const float* head_w = (const float*)d_in[17];
  const float* head_b = (const float*)d_in[18];
  float* out = (float*)d_out;

  // workspace layout (~213 MB)
  char* p = (char*)d_ws;
  float* x = (float*)p;             p += (size_t)16384 * 512 * 4;   // fp32 master
  unsigned short* xb = (unsigned short*)p; p += (size_t)16384 * 512 * 2;  // bf16 of x
  unsigned short* qkv = (unsigned short*)p;                         // [16384,1536] bf16
  float* y = (float*)qkv;           // fp32 [16384,512] aliases qkv (disjoint lifetimes)
  p += (size_t)16384 * 1536 * 2;
  unsigned short* attno = (unsigned short*)p; p += (size_t)16384 * 512 * 2;
  unsigned short* h = (unsigned short*)p;     p += (size_t)16384 * 2048 * 2;
  unsigned short* P = h;            // [512,256,256] bf16 aliases h (disjoint lifetimes)
  unsigned short* wq = (unsigned short*)p;    p += (size_t)4718592 * 2;
  unsigned short* wo = (unsigned short*)p;    p += (size_t)1572864 * 2;
  unsigned short* wf1 = (unsigned short*)p;   p += (size_t)6291456 * 2;
  unsigned short* wf2 = (unsigned short*)p;   p += (size_t)6291456 * 2;
  float* mem = (float*)p;           p += (size_t)16384 * 4;

  cvt4_kernel<<<4608, 256, 0, stream>>>(qkv_w, wq);
  cvt4_kernel<<<1536, 256, 0, stream>>>(out_w, wo);
  cvt4_kernel<<<6144, 256, 0, stream>>>(ff1_w, wf1);
  cvt4_kernel<<<6144, 256, 0, stream>>>(ff2_w, wf2);

  embed_kernel<<<16384, 512, 0, stream>>>(src_pad, emb_w, emb_b, x, xb);

  for (int l = 0; l < 6; l++) {
    gemm_nt<0, 1, 0><<<dim3(12, 128), 256, 0, stream>>>(
        xb, wq + (size_t)l * 786432, qkv_b + (size_t)l * 1536, nullptr,
        nullptr, qkv, 16384, 1536, 512);
    qk_kernel<<<2048, 256, 0, stream>>>(qkv, P);
    pv_kernel<<<2048, 256, 0, stream>>>(qkv, P, attno);
    gemm_nt<0, 0, 1><<<dim3(4, 128), 256, 0, stream>>>(
        attno, wo + (size_t)l * 262144, out_b + (size_t)l * 512, x,
        y, nullptr, 16384, 512, 512);
    ln_kernel<<<16384, 256, 0, stream>>>(y, ln1_g + (size_t)l * 512,
                                         ln1_b + (size_t)l * 512, x, xb);
    gemm_nt<1, 1, 0><<<dim3(16, 128), 256, 0, stream>>>(
        xb, wf1 + (size_t)l * 1048576, ff1_b + (size_t)l * 2048, nullptr,
        nullptr, h, 16384, 2048, 512);
    gemm_nt<0, 0, 1><<<dim3(4, 128), 256, 0, stream>>>(
        h, wf2 + (size_t)l * 1048576, ff2_b + (size_t)l * 512, x,
        y, nullptr, 16384, 512, 2048);
    ln_kernel<<<16384, 256, 0, stream>>>(y, ln2_g + (size_t)l * 512,
                                         ln2_b + (size_t)l * 512, x, xb);
  }

  zero_kernel<<<64, 256, 0, stream>>>(mem);
  latent_gemm<<<dim3(4, 128), 256, 0, stream>>>(xb, lat_w, mem);
  head_kernel<<<64, 256, 0, stream>>>(mem, lat_b, head_w, head_b, out);
}